// Round 8
// baseline (287.638 us; speedup 1.0000x reference)
//
#include <hip/hip_runtime.h>
#include <float.h>

// Problem constants
#define DIM   512
#define HW    1024
#define NCB   8
#define VOC   1024
#define DCB   64

#define THREADS   256
#define POS_TILE  128
#define VCHUNK    128
#define NCHUNK    8
#define CAP       16
#define MARGIN    0.012f

#define Q_ELEMS   8388608
#define I_ELEMS   131072
#define C_OFFSET  8519680

// workspace layout (bytes)
#define WS_DONE_OFF   0          // unsigned doneCnt
#define WS_SLOT_OFF   256        // float slots[64]
#define WS_CC_OFF     1024       // float ccTab[8192]
#define WS_CB_OFF     33792     // ushort cbkBf[8*1024*64] fragment-ordered, ~1.03 MB

typedef __attribute__((ext_vector_type(8))) short          short8;
typedef __attribute__((ext_vector_type(8))) unsigned short ushort8;
typedef __attribute__((ext_vector_type(4))) float          floatx4;

// f32 -> bf16 RNE
__device__ __forceinline__ unsigned short f2bf(float f) {
    unsigned u = __builtin_bit_cast(unsigned, f);
    unsigned r = u + 0x7FFFu + ((u >> 16) & 1u);
    return (unsigned short)(r >> 16);
}

// ---- K0: np-exact code norms + bf16(-2*c) codebook in MFMA-fragment order ----
// 32 blocks x 256 threads; block handles 256 codebook rows via LDS transpose.
__global__ __launch_bounds__(256) void vq_prep_kernel(const float* __restrict__ cbk,
                                                      unsigned* __restrict__ doneCnt,
                                                      float* __restrict__ slots,
                                                      float* __restrict__ cc,
                                                      unsigned short* __restrict__ cbkBf) {
#pragma clang fp contract(off)
    __shared__ float zr[256 * 65];            // stride 65: bank-conflict-free column reads
    const int tid   = threadIdx.x;
    const int rows0 = blockIdx.x * 256;

    if (blockIdx.x == 0 && tid < 65) {
        if (tid == 0) *doneCnt = 0u;
        else slots[tid - 1] = 0.f;
    }

    // stage 256 rows x 64 f32, coalesced float4 loads
    for (int i = 0; i < 16; ++i) {
        int e4  = i * 256 + tid;              // 0..4095
        int row = e4 >> 4;
        int k4  = (e4 & 15) * 4;
        float4 v = ((const float4*)cbk)[(long)rows0 * 16 + e4];
        zr[row * 65 + k4 + 0] = v.x;
        zr[row * 65 + k4 + 1] = v.y;
        zr[row * 65 + k4 + 2] = v.z;
        zr[row * 65 + k4 + 3] = v.w;
    }
    __syncthreads();

    // np-exact cc, one thread per row (streamed r[8], exact np pairwise order)
    {
        const float* c = &zr[tid * 65];
        float r[8];
#pragma unroll
        for (int j = 0; j < 8; ++j) { float v = c[j]; r[j] = v * v; }
#pragma unroll
        for (int i = 1; i < 8; ++i)
#pragma unroll
            for (int j = 0; j < 8; ++j) { float v = c[i * 8 + j]; r[j] = r[j] + v * v; }
        cc[rows0 + tid] = ((r[0] + r[1]) + (r[2] + r[3])) + ((r[4] + r[5]) + (r[6] + r[7]));
    }

    // bf16(-2*c) in fragment order: dst = cbIdx*65536 + (((chunk*8+ct)*2+ks)*64 + lg*16 + l15)*8
#pragma unroll
    for (int it = 0; it < 8; ++it) {
        int row = it * 32 + (tid >> 3);       // 0..255
        int g8  = tid & 7;                    // k-group of 8
        ushort8 w;
#pragma unroll
        for (int e = 0; e < 8; ++e) w[e] = f2bf(-2.0f * zr[row * 65 + g8 * 8 + e]);
        int g     = rows0 + row;              // global 0..8191
        int code  = g & 1023;
        int chunk = code >> 7, ct = (code >> 4) & 7, l15 = code & 15;
        int ks    = g8 >> 2,  lg = g8 & 3;
        long dst = (long)(g >> 10) * 65536 +
                   ((((chunk * 8 + ct) * 2 + ks) * 64) + lg * 16 + l15) * 8;
        *(ushort8*)&cbkBf[dst] = w;
    }
}

// streamed np einsum-dist vs global-strided z column
__device__ __forceinline__ float np_dist_g(const float* zp, const float4* cr,
                                           float zz, float ccv) {
#pragma clang fp contract(off)
    float p[16];
#pragma unroll
    for (int l = 0; l < 16; ++l) p[l] = 0.f;
#pragma unroll
    for (int j = 0; j < 4; ++j) {
        float4 c0 = cr[j * 4 + 0], c1 = cr[j * 4 + 1];
        float4 c2 = cr[j * 4 + 2], c3 = cr[j * 4 + 3];
        float cl[16] = {c0.x, c0.y, c0.z, c0.w, c1.x, c1.y, c1.z, c1.w,
                        c2.x, c2.y, c2.z, c2.w, c3.x, c3.y, c3.z, c3.w};
#pragma unroll
        for (int l = 0; l < 16; ++l)
            p[l] = __builtin_fmaf(zp[(long)(j * 16 + l) * HW], cl[l], p[l]);
    }
    float s8[8], s4[4];
#pragma unroll
    for (int l = 0; l < 8; ++l) s8[l] = p[l] + p[l + 8];
#pragma unroll
    for (int l = 0; l < 4; ++l) s4[l] = s8[l] + s8[l + 4];
    float u0 = s4[0] + s4[2];
    float u1 = s4[1] + s4[3];
    float E  = u0 + u1;
    float t  = zz - 2.0f * E;
    return t + ccv;
}

// LDS (all wave-private after the single staging barrier)
struct SmemT {
    unsigned short zsb[POS_TILE * DCB];      // 16384 B  bf16 z [pos][k^swz]
    unsigned       candI[POS_TILE * CAP];    //  8192 B
    unsigned       cnt[POS_TILE];            //   512 B
};                                            // 25088 B

// ---- K1: barrier-free MFMA scan (codes direct from L2) + np refine + outputs ----
__global__ __launch_bounds__(THREADS, 4) void vq_main_kernel(
    const float* __restrict__ z, const float* __restrict__ cbk,
    const float* __restrict__ ccTab, const unsigned short* __restrict__ cbkBf,
    float* __restrict__ slots, unsigned* __restrict__ doneCnt,
    float* __restrict__ out)
{
    __shared__ SmemT sm;

    const int tid   = threadIdx.x;
    const int lane  = tid & 63;
    const int wid   = tid >> 6;            // 4 waves
    const int l15   = lane & 15;
    const int lg    = lane >> 4;           // 0..3
    const int wpos0 = wid * 32;            // wave owns 32 positions
    const int cb    = blockIdx.x & 7;      // == XCD id: per-XCD L2 holds its own codebook slice
    const int tile  = blockIdx.x >> 3;
    const int b     = tile >> 3;
    const int hw0   = (tile & 7) * POS_TILE;

    const long zBase  = (long)b * (DIM * HW) + (long)cb * DCB * HW + hw0;
    const long cbBase = (long)cb * (VOC * DCB);
    const unsigned short* cbA  = cbkBf + (long)cb * 65536;   // fragment-ordered -2c
    const float*          ccRow = ccTab + cb * VOC;

    // ---- cooperative z staging: bf16 [pos][k ^ (pos&7)<<3] ----
    for (int i = 0; i < 16; ++i) {
        int e   = i * THREADS + tid;       // 0..4095
        int kp  = e >> 7;                  // 0..31
        int pos = e & 127;
        int k   = kp * 2;
        float v0 = z[zBase + (long)k * HW + pos];
        float v1 = z[zBase + (long)(k + 1) * HW + pos];
        unsigned pack = (unsigned)f2bf(v0) | ((unsigned)f2bf(v1) << 16);
        *(unsigned*)&sm.zsb[pos * 64 + (k ^ ((pos & 7) << 3))] = pack;
    }
    if (tid < POS_TILE) sm.cnt[tid] = 0;
    __syncthreads();                       // the ONLY barrier

    // hoist z fragments (chunk-invariant): bz[pt][ks]
    short8 bz[2][2];
#pragma unroll
    for (int pt = 0; pt < 2; ++pt)
#pragma unroll
        for (int ks = 0; ks < 2; ++ks) {
            int row = wpos0 + pt * 16 + l15;
            bz[pt][ks] = *(const short8*)&sm.zsb[row * 64 + ((ks * 32 + lg * 8) ^ ((row & 7) << 3))];
        }

    float runBest[2] = {FLT_MAX, FLT_MAX};

    for (int chunk = 0; chunk < NCHUNK; ++chunk) {
        floatx4 acc[8][2];
#pragma unroll
        for (int ct = 0; ct < 8; ++ct) {
            float4 ci = *(const float4*)&ccRow[chunk * VCHUNK + ct * 16 + lg * 4];
            floatx4 a = {ci.x, ci.y, ci.z, ci.w};
            acc[ct][0] = a; acc[ct][1] = a;
        }
#pragma unroll
        for (int ks = 0; ks < 2; ++ks)
#pragma unroll
            for (int ct = 0; ct < 8; ++ct) {
                short8 ac = *(const short8*)&cbA[((((chunk * 8 + ct) * 2 + ks) << 6) + lane) << 3];
#pragma unroll
                for (int pt = 0; pt < 2; ++pt)
                    acc[ct][pt] = __builtin_amdgcn_mfma_f32_16x16x32_bf16(ac, bz[pt][ks], acc[ct][pt], 0, 0, 0);
            }

        // per-pos chunk min -> running min -> collect within margin
#pragma unroll
        for (int pt = 0; pt < 2; ++pt) {
            float m = acc[0][pt][0];
#pragma unroll
            for (int ct = 0; ct < 8; ++ct)
#pragma unroll
                for (int r = 0; r < 4; ++r) m = fminf(m, acc[ct][pt][r]);
            m = fminf(m, __shfl_xor(m, 16, 64));
            m = fminf(m, __shfl_xor(m, 32, 64));
            runBest[pt] = fminf(runBest[pt], m);
            const float thr = runBest[pt] + MARGIN;
            const int pos = wpos0 + pt * 16 + l15;
#pragma unroll
            for (int ct = 0; ct < 8; ++ct)
#pragma unroll
                for (int r = 0; r < 4; ++r) {
                    if (acc[ct][pt][r] <= thr) {
                        unsigned idx  = chunk * VCHUNK + ct * 16 + lg * 4 + r;
                        unsigned slot = atomicAdd(&sm.cnt[pos], 1u);
                        if (slot < CAP) sm.candI[pos * CAP + slot] = idx;
                    }
                }
        }
    }

    // ---- np-exact refine: lanes 0-31 handle the wave's 32 positions ----
    unsigned bi = 0xFFFFFFFFu;
    if (lane < 32) {
        const int pos = wpos0 + lane;
        const float* zp = z + zBase + pos;
        float zz;
        {
#pragma clang fp contract(off)
            float r[8];
#pragma unroll
            for (int j = 0; j < 8; ++j) { float v = zp[(long)j * HW]; r[j] = v * v; }
#pragma unroll
            for (int i = 1; i < 8; ++i)
#pragma unroll
                for (int j = 0; j < 8; ++j) {
                    float v = zp[(long)(i * 8 + j) * HW];
                    r[j] = r[j] + v * v;
                }
            zz = ((r[0] + r[1]) + (r[2] + r[3])) + ((r[4] + r[5]) + (r[6] + r[7]));
        }
        const unsigned n = sm.cnt[pos];
        float bd = FLT_MAX;
        if (n <= CAP) {
            for (unsigned s = 0; s < n; ++s) {
                unsigned vi = sm.candI[pos * CAP + s];
                float d = np_dist_g(zp, (const float4*)(cbk + cbBase + (long)vi * DCB),
                                    zz, ccRow[vi]);
                if (d < bd || (d == bd && vi < bi)) { bd = d; bi = vi; }
            }
        } else {  // overflow fallback: np-exact ascending rescan (= np first-index order)
            for (unsigned vi = 0; vi < VOC; ++vi) {
                float d = np_dist_g(zp, (const float4*)(cbk + cbBase + (long)vi * DCB),
                                    zz, ccRow[vi]);
                if (d < bd) { bd = d; bi = vi; }
            }
        }
        out[Q_ELEMS + (long)b * (NCB * HW) + cb * HW + hw0 + pos] = (float)bi;
    }

    // ---- epilogue: q gather + straight-through store + commitment ----
    const unsigned vi = (unsigned)__shfl((int)bi, lane & 31, 64);
    {
        const int posl  = lane & 31;
        const int pos   = wpos0 + posl;
        const int khalf = lane >> 5;
        const float* crow = cbk + cbBase + (long)vi * DCB + khalf * 32;
        const float* zp   = z + zBase + pos + (long)khalf * 32 * HW;
        float* qp = out + (long)b * (DIM * HW) + (long)(cb * DCB + khalf * 32) * HW + hw0 + pos;
        float csum = 0.f;
#pragma unroll
        for (int j4 = 0; j4 < 8; ++j4) {
            float4 cv = *(const float4*)(crow + j4 * 4);
            float z0 = zp[(long)(j4 * 4 + 0) * HW];
            float z1 = zp[(long)(j4 * 4 + 1) * HW];
            float z2 = zp[(long)(j4 * 4 + 2) * HW];
            float z3 = zp[(long)(j4 * 4 + 3) * HW];
            qp[(long)(j4 * 4 + 0) * HW] = (cv.x - z0) + z0;
            qp[(long)(j4 * 4 + 1) * HW] = (cv.y - z1) + z1;
            qp[(long)(j4 * 4 + 2) * HW] = (cv.z - z2) + z2;
            qp[(long)(j4 * 4 + 3) * HW] = (cv.w - z3) + z3;
            float d0 = z0 - cv.x; csum = fmaf(d0, d0, csum);
            float d1 = z1 - cv.y; csum = fmaf(d1, d1, csum);
            float d2 = z2 - cv.z; csum = fmaf(d2, d2, csum);
            float d3 = z3 - cv.w; csum = fmaf(d3, d3, csum);
        }
#pragma unroll
        for (int m = 1; m < 64; m <<= 1) csum += __shfl_xor(csum, m, 64);

        if (lane == 0) {
            atomicAdd(&slots[(blockIdx.x * 4 + wid) & 63], csum);
            __threadfence();
            unsigned d = atomicAdd(doneCnt, 1u);
            if (d == 4095u) {               // last wave finalizes
                __threadfence();
                float tot = 0.f;
                for (int s = 0; s < 64; ++s) tot += slots[s];
                out[C_OFFSET] = tot * (1.0f / 8388608.0f);
            }
        }
    }
}

extern "C" void kernel_launch(void* const* d_in, const int* in_sizes, int n_in,
                              void* d_out, int out_size, void* d_ws, size_t ws_size,
                              hipStream_t stream) {
    (void)in_sizes; (void)n_in; (void)out_size; (void)ws_size;
    const float* z   = (const float*)d_in[0];
    const float* cbk = (const float*)d_in[1];
    float* out = (float*)d_out;
    char*  ws  = (char*)d_ws;
    unsigned*       doneCnt = (unsigned*)(ws + WS_DONE_OFF);
    float*          slots   = (float*)(ws + WS_SLOT_OFF);
    float*          ccTab   = (float*)(ws + WS_CC_OFF);
    unsigned short* cbkBf   = (unsigned short*)(ws + WS_CB_OFF);

    vq_prep_kernel<<<dim3(32), dim3(256), 0, stream>>>(cbk, doneCnt, slots, ccTab, cbkBf);
    vq_main_kernel<<<dim3(1024), dim3(THREADS), 0, stream>>>(z, cbk, ccTab, cbkBf,
                                                             slots, doneCnt, out);
}